// Round 10
// baseline (631.844 us; speedup 1.0000x reference)
//
#include <hip/hip_runtime.h>

#define S_LEN 2048
#define R_LEN 384
#define C_DIM 64

typedef unsigned short u16;
typedef unsigned int u32;
typedef __attribute__((ext_vector_type(8))) short s8v;
typedef __attribute__((ext_vector_type(4))) float f4v;

__device__ __forceinline__ float bf2f(u16 h) {
    union { u32 u; float f; } c; c.u = ((u32)h) << 16; return c.f;
}
__device__ __forceinline__ u16 f2bf(float f) {
    union { float f; u32 u; } c; c.f = f;
    return (u16)((c.u + 0x7fffu + ((c.u >> 16) & 1u)) >> 16);
}
__device__ __forceinline__ void unpack8(uint4 q, float* o) {
    o[0] = bf2f((u16)(q.x & 0xffffu)); o[1] = bf2f((u16)(q.x >> 16));
    o[2] = bf2f((u16)(q.y & 0xffffu)); o[3] = bf2f((u16)(q.y >> 16));
    o[4] = bf2f((u16)(q.z & 0xffffu)); o[5] = bf2f((u16)(q.z >> 16));
    o[6] = bf2f((u16)(q.w & 0xffffu)); o[7] = bf2f((u16)(q.w >> 16));
}
__device__ __forceinline__ void split8(const float* y, uint4& qh, uint4& ql) {
    u16 h[8]; u16 l[8];
    #pragma unroll
    for (int j = 0; j < 8; ++j) {
        h[j] = f2bf(y[j]);
        l[j] = f2bf(y[j] - bf2f(h[j]));
    }
    qh.x = (u32)h[0] | ((u32)h[1] << 16); qh.y = (u32)h[2] | ((u32)h[3] << 16);
    qh.z = (u32)h[4] | ((u32)h[5] << 16); qh.w = (u32)h[6] | ((u32)h[7] << 16);
    ql.x = (u32)l[0] | ((u32)l[1] << 16); ql.y = (u32)l[2] | ((u32)l[3] << 16);
    ql.z = (u32)l[4] | ((u32)l[5] << 16); ql.w = (u32)l[6] | ((u32)l[7] << 16);
}
__device__ __forceinline__ void load8f(const float* p, float* o) {
    float4 a = *(const float4*)p;
    float4 b = *(const float4*)(p + 4);
    o[0] = a.x; o[1] = a.y; o[2] = a.z; o[3] = a.w;
    o[4] = b.x; o[5] = b.y; o[6] = b.z; o[7] = b.w;
}
// split a float weight into bf16 hi + bf16 lo
__device__ __forceinline__ void wsplit(float v, short& h, short& l) {
    u16 hh = f2bf(v);
    h = (short)hh;
    l = (short)f2bf(v - bf2f(hh));
}
// xs tile: [rows][64 bf16] = 128 B/row; XOR-swizzle 16B slots by row&7
#define XS_SWZ(row, bc) ((((int)(row)) << 7) + (((int)(bc)) ^ ((((int)(row)) & 7) << 4)))

// ---- KA: LN + kv (hi/lo x hi/lo MFMA -> ws) + q_avg partial sums (atomic) ----
__global__ __launch_bounds__(256) void ka_lnkv(
    const float* __restrict__ act, const float* __restrict__ lnsp, const float* __restrict__ lnbp,
    const float* __restrict__ wk, const float* __restrict__ wv,
    u16* __restrict__ kv_g, float* __restrict__ qavg_g)
{
    __shared__ __align__(16) char xs[16384];       // 128 rows x 64 bf16 (hi), swizzled
    __shared__ __align__(16) char xsl[16384];      // lo residuals
    __shared__ float scrW[4][64];
    const int t = threadIdx.x;
    const int r = blockIdx.x;
    const int s0 = blockIdx.y * 128;
    const int lane = t & 63;
    const int w = t >> 6;
    const int grp = t & 7;
    const int rowb = t >> 3;
    const int n16 = lane & 15;
    const int kgrp = lane >> 4;

    float lns_r[8], lnb_r[8];
    load8f(lnsp + grp * 8, lns_r);
    load8f(lnbp + grp * 8, lnb_r);

    // B fragments hi/lo: B[k][n] = wk[k][n] (n<8) | wv[k][n-8]
    s8v bkv0h, bkv1h, bkv0l, bkv1l;
    #pragma unroll
    for (int j = 0; j < 8; ++j) {
        int k0 = (kgrp << 3) + j;
        float e0 = (n16 < 8) ? wk[k0 * 8 + n16] : wv[k0 * 8 + (n16 - 8)];
        float e1 = (n16 < 8) ? wk[(k0 + 32) * 8 + n16] : wv[(k0 + 32) * 8 + (n16 - 8)];
        short h, l;
        wsplit(e0, h, l); bkv0h[j] = h; bkv0l[j] = l;
        wsplit(e1, h, l); bkv1h[j] = h; bkv1l[j] = l;
    }

    float qacc[8];
    #pragma unroll
    for (int j = 0; j < 8; ++j) qacc[j] = 0.f;

    #pragma unroll
    for (int sub = 0; sub < 4; ++sub) {
        int row = sub * 32 + rowb;
        int s = s0 + row;
        float xf[8];
        load8f(act + ((size_t)s * R_LEN + r) * C_DIM + grp * 8, xf);
        float sum = 0.f, sq = 0.f;
        #pragma unroll
        for (int j = 0; j < 8; ++j) { sum += xf[j]; sq += xf[j] * xf[j]; }
        #pragma unroll
        for (int m = 1; m <= 4; m <<= 1) { sum += __shfl_xor(sum, m); sq += __shfl_xor(sq, m); }
        float mu = sum * (1.f / 64.f);
        float var = sq * (1.f / 64.f) - mu * mu;
        float rstd = rsqrtf(var + 1e-5f);
        float yv[8];
        #pragma unroll
        for (int j = 0; j < 8; ++j) {
            yv[j] = (xf[j] - mu) * rstd * lns_r[j] + lnb_r[j];
            qacc[j] += yv[j];
        }
        uint4 qh, ql; split8(yv, qh, ql);
        *(uint4*)(xs  + XS_SWZ(row, grp * 16)) = qh;
        *(uint4*)(xsl + XS_SWZ(row, grp * 16)) = ql;
    }
    __syncthreads();

    // kv = X @ [wk|wv]: Ah*Bh + Al*Bh + Ah*Bl (fp32-accurate); 2 tiles/wave
    #pragma unroll
    for (int i4 = 0; i4 < 2; ++i4) {
        int tile = w * 2 + i4;
        s8v a0h = *(const s8v*)(xs  + XS_SWZ(tile * 16 + n16, kgrp * 16));
        s8v a1h = *(const s8v*)(xs  + XS_SWZ(tile * 16 + n16, 64 + kgrp * 16));
        s8v a0l = *(const s8v*)(xsl + XS_SWZ(tile * 16 + n16, kgrp * 16));
        s8v a1l = *(const s8v*)(xsl + XS_SWZ(tile * 16 + n16, 64 + kgrp * 16));
        f4v acc = {0.f, 0.f, 0.f, 0.f};
        acc = __builtin_amdgcn_mfma_f32_16x16x32_bf16(a0h, bkv0h, acc, 0, 0, 0);
        acc = __builtin_amdgcn_mfma_f32_16x16x32_bf16(a1h, bkv1h, acc, 0, 0, 0);
        acc = __builtin_amdgcn_mfma_f32_16x16x32_bf16(a0l, bkv0h, acc, 0, 0, 0);
        acc = __builtin_amdgcn_mfma_f32_16x16x32_bf16(a1l, bkv1h, acc, 0, 0, 0);
        acc = __builtin_amdgcn_mfma_f32_16x16x32_bf16(a0h, bkv0l, acc, 0, 0, 0);
        acc = __builtin_amdgcn_mfma_f32_16x16x32_bf16(a1h, bkv1l, acc, 0, 0, 0);
        #pragma unroll
        for (int jj = 0; jj < 4; ++jj) {
            int sg = s0 + tile * 16 + kgrp * 4 + jj;
            kv_g[((size_t)r * S_LEN + sg) * 16 + n16] = f2bf(acc[jj]);
        }
    }

    // q_avg partials: reduce lanes sharing grp (masks 8,16,32), cross-wave, atomics
    #pragma unroll
    for (int m = 8; m <= 32; m <<= 1) {
        #pragma unroll
        for (int j = 0; j < 8; ++j) qacc[j] += __shfl_xor(qacc[j], m);
    }
    if (lane < 8) {
        #pragma unroll
        for (int j = 0; j < 8; ++j) scrW[w][lane * 8 + j] = qacc[j];
    }
    __syncthreads();
    if (t < 64) {
        float v = scrW[0][t] + scrW[1][t] + scrW[2][t] + scrW[3][t];
        atomicAdd(&qavg_g[r * 64 + t], v);
    }
}

// ---- KB: q = (q_avg @ wq)*scale; softmax over S; o1 -> ws ----
__global__ __launch_bounds__(256) void kb_attn(
    const u16* __restrict__ kv_g, const float* __restrict__ qavg_g,
    const float* __restrict__ wq, float* __restrict__ o1g)
{
    __shared__ __align__(16) char kvb[65536];      // kv [2048][16] bf16, swizzled
    __shared__ float scrA[256 * 8];
    __shared__ float scrC[4 * 64];
    __shared__ float qlds[64];
    const int t = threadIdx.x;
    const int r = blockIdx.x;
    const int lane = t & 63;
    const int w = t >> 6;

    // stage kv[r] -> LDS (coalesced 16B loads)
    #pragma unroll
    for (int i = 0; i < 16; ++i) {
        int f = i * 256 + t;
        int s = f >> 1, half = f & 1;
        uint4 q = *(const uint4*)((const char*)kv_g + (size_t)r * 65536 + (size_t)f * 16);
        *(uint4*)(kvb + s * 32 + ((half << 4) ^ (((s >> 2) & 1) << 4))) = q;
    }
    if (t < 64) {
        float s = 0.f;
        for (int c = 0; c < 64; ++c) s += qavg_g[r * 64 + c] * wq[c * 64 + t];
        qlds[t] = s * (0.35355339059327373f / (float)S_LEN);
    }
    __syncthreads();

    float q_r[64];
    #pragma unroll
    for (int c = 0; c < 64; ++c) q_r[c] = qlds[c];

    // pass A: per-head max
    float mx[8];
    #pragma unroll
    for (int h = 0; h < 8; ++h) mx[h] = -1e30f;
    for (int i = 0; i < 8; ++i) {
        int s = i * 256 + t;
        int sw = ((s >> 2) & 1) << 4;
        float kf[8]; unpack8(*(const uint4*)(kvb + s * 32 + sw), kf);
        #pragma unroll
        for (int h = 0; h < 8; ++h) {
            float lg = 0.f;
            #pragma unroll
            for (int a = 0; a < 8; ++a) lg += q_r[h * 8 + a] * kf[a];
            mx[h] = fmaxf(mx[h], lg);
        }
    }
    #pragma unroll
    for (int h = 0; h < 8; ++h) scrA[t * 8 + h] = mx[h];
    __syncthreads();
    for (int st = 128; st >= 1; st >>= 1) {
        if (t < st) {
            #pragma unroll
            for (int h = 0; h < 8; ++h)
                scrA[t * 8 + h] = fmaxf(scrA[t * 8 + h], scrA[(t + st) * 8 + h]);
        }
        __syncthreads();
    }
    float mxf[8];
    #pragma unroll
    for (int h = 0; h < 8; ++h) mxf[h] = scrA[h];
    __syncthreads();

    // pass B: exp-sum + o1 accumulation
    float sm[8];
    float o1a[64];
    #pragma unroll
    for (int h = 0; h < 8; ++h) sm[h] = 0.f;
    #pragma unroll
    for (int e = 0; e < 64; ++e) o1a[e] = 0.f;
    for (int i = 0; i < 8; ++i) {
        int s = i * 256 + t;
        int sw = ((s >> 2) & 1) << 4;
        float kf[8]; unpack8(*(const uint4*)(kvb + s * 32 + sw), kf);
        float vf[8]; unpack8(*(const uint4*)(kvb + s * 32 + (16 ^ sw)), vf);
        #pragma unroll
        for (int h = 0; h < 8; ++h) {
            float lg = 0.f;
            #pragma unroll
            for (int a = 0; a < 8; ++a) lg += q_r[h * 8 + a] * kf[a];
            float p = __expf(lg - mxf[h]);
            sm[h] += p;
            #pragma unroll
            for (int a = 0; a < 8; ++a) o1a[h * 8 + a] += p * vf[a];
        }
    }
    #pragma unroll
    for (int h = 0; h < 8; ++h) scrA[t * 8 + h] = sm[h];
    __syncthreads();
    for (int st = 128; st >= 1; st >>= 1) {
        if (t < st) {
            #pragma unroll
            for (int h = 0; h < 8; ++h)
                scrA[t * 8 + h] += scrA[(t + st) * 8 + h];
        }
        __syncthreads();
    }
    #pragma unroll
    for (int m = 1; m < 64; m <<= 1) {
        #pragma unroll
        for (int e = 0; e < 64; ++e) o1a[e] += __shfl_xor(o1a[e], m);
    }
    #pragma unroll
    for (int e = 0; e < 64; ++e) if (lane == e) scrC[w * 64 + e] = o1a[e];
    __syncthreads();
    if (t < 64) {
        float v = scrC[t] + scrC[64 + t] + scrC[128 + t] + scrC[192 + t];
        o1g[r * 64 + t] = v / scrA[t >> 3];
    }
}

// ---- KC: gate = sigmoid(LN(x)@wg+bg); out = (gate*o1)@wo + bo ----
// Both GEMMs hi/lo x hi/lo (Ah*Bh + Al*Bh + Ah*Bl): ~fp32-accurate.
__global__ __launch_bounds__(256) void kc_gateout(
    const float* __restrict__ act, const float* __restrict__ lnsp, const float* __restrict__ lnbp,
    const float* __restrict__ wg, const float* __restrict__ bgp,
    const float* __restrict__ wo, const float* __restrict__ bop,
    const float* __restrict__ o1g, float* __restrict__ out)
{
    __shared__ __align__(16) char bufH[16384];   // 128 rows hi bf16 (act -> tmp), swizzled
    __shared__ __align__(16) char bufL[16384];   // lo residuals
    const int t = threadIdx.x;
    const int r = blockIdx.x;
    const int s0 = blockIdx.y * 128;
    const int lane = t & 63;
    const int w = t >> 6;
    const int grp = t & 7;
    const int rowb = t >> 3;
    const int n16 = lane & 15;
    const int kgrp = lane >> 4;

    float lns_r[8], lnb_r[8];
    load8f(lnsp + grp * 8, lns_r);
    load8f(lnbp + grp * 8, lnb_r);

    float o1c[4], bgc[4], boc[4];
    #pragma unroll
    for (int c4 = 0; c4 < 4; ++c4) {
        int col = c4 * 16 + n16;
        o1c[c4] = o1g[r * 64 + col];
        bgc[c4] = bgp[col];
        boc[c4] = bop[col];
    }

    // stage LN'd rows (bf16 hi+lo, swizzled)
    #pragma unroll
    for (int sub = 0; sub < 4; ++sub) {
        int row = sub * 32 + rowb;
        int s = s0 + row;
        float xf[8];
        load8f(act + ((size_t)s * R_LEN + r) * C_DIM + grp * 8, xf);
        float sum = 0.f, sq = 0.f;
        #pragma unroll
        for (int j = 0; j < 8; ++j) { sum += xf[j]; sq += xf[j] * xf[j]; }
        #pragma unroll
        for (int m = 1; m <= 4; m <<= 1) { sum += __shfl_xor(sum, m); sq += __shfl_xor(sq, m); }
        float mu = sum * (1.f / 64.f);
        float var = sq * (1.f / 64.f) - mu * mu;
        float rstd = rsqrtf(var + 1e-5f);
        float yv[8];
        #pragma unroll
        for (int j = 0; j < 8; ++j) yv[j] = (xf[j] - mu) * rstd * lns_r[j] + lnb_r[j];
        uint4 qh, ql; split8(yv, qh, ql);
        *(uint4*)(bufH + XS_SWZ(row, grp * 16)) = qh;
        *(uint4*)(bufL + XS_SWZ(row, grp * 16)) = ql;
    }
    __syncthreads();

    // GEMM1: tmp = sigmoid(X@wg + bg) * o1, wave-private tiles.
    // wg hi/lo fragments scoped here so their registers die before wo's load.
    {
        s8v wgh[4][2], wgl[4][2];
        #pragma unroll
        for (int c4 = 0; c4 < 4; ++c4) {
            #pragma unroll
            for (int kb = 0; kb < 2; ++kb) {
                #pragma unroll
                for (int j = 0; j < 8; ++j) {
                    int k = kb * 32 + kgrp * 8 + j;
                    short h, l;
                    wsplit(wg[k * 64 + c4 * 16 + n16], h, l);
                    wgh[c4][kb][j] = h; wgl[c4][kb][j] = l;
                }
            }
        }
        #pragma unroll
        for (int i4 = 0; i4 < 2; ++i4) {
            int tile = w * 2 + i4;
            s8v a0h = *(const s8v*)(bufH + XS_SWZ(tile * 16 + n16, kgrp * 16));
            s8v a1h = *(const s8v*)(bufH + XS_SWZ(tile * 16 + n16, 64 + kgrp * 16));
            s8v a0l = *(const s8v*)(bufL + XS_SWZ(tile * 16 + n16, kgrp * 16));
            s8v a1l = *(const s8v*)(bufL + XS_SWZ(tile * 16 + n16, 64 + kgrp * 16));
            #pragma unroll
            for (int c4 = 0; c4 < 4; ++c4) {
                f4v acc = {0.f, 0.f, 0.f, 0.f};
                acc = __builtin_amdgcn_mfma_f32_16x16x32_bf16(a0h, wgh[c4][0], acc, 0, 0, 0);
                acc = __builtin_amdgcn_mfma_f32_16x16x32_bf16(a1h, wgh[c4][1], acc, 0, 0, 0);
                acc = __builtin_amdgcn_mfma_f32_16x16x32_bf16(a0l, wgh[c4][0], acc, 0, 0, 0);
                acc = __builtin_amdgcn_mfma_f32_16x16x32_bf16(a1l, wgh[c4][1], acc, 0, 0, 0);
                acc = __builtin_amdgcn_mfma_f32_16x16x32_bf16(a0h, wgl[c4][0], acc, 0, 0, 0);
                acc = __builtin_amdgcn_mfma_f32_16x16x32_bf16(a1h, wgl[c4][1], acc, 0, 0, 0);
                #pragma unroll
                for (int jj = 0; jj < 4; ++jj) {
                    float gv = acc[jj] + bgc[c4];
                    float sg = 1.f / (1.f + __expf(-gv));
                    float tv = sg * o1c[c4];
                    u16 th = f2bf(tv);
                    u16 tl = f2bf(tv - bf2f(th));
                    int row = tile * 16 + kgrp * 4 + jj;
                    int off = XS_SWZ(row, (c4 * 16 + n16) * 2);
                    *(u16*)(bufH + off) = th;
                    *(u16*)(bufL + off) = tl;
                }
            }
        }
    }
    // tiles are wave-private: no block sync needed between GEMM1 and GEMM2

    // GEMM2: out = tmp @ wo + bo, direct fp32 stores
    {
        s8v woh[4][2], wol[4][2];
        #pragma unroll
        for (int c4 = 0; c4 < 4; ++c4) {
            #pragma unroll
            for (int kb = 0; kb < 2; ++kb) {
                #pragma unroll
                for (int j = 0; j < 8; ++j) {
                    int k = kb * 32 + kgrp * 8 + j;
                    short h, l;
                    wsplit(wo[k * 64 + c4 * 16 + n16], h, l);
                    woh[c4][kb][j] = h; wol[c4][kb][j] = l;
                }
            }
        }
        #pragma unroll
        for (int i4 = 0; i4 < 2; ++i4) {
            int tile = w * 2 + i4;
            s8v a0h = *(const s8v*)(bufH + XS_SWZ(tile * 16 + n16, kgrp * 16));
            s8v a1h = *(const s8v*)(bufH + XS_SWZ(tile * 16 + n16, 64 + kgrp * 16));
            s8v a0l = *(const s8v*)(bufL + XS_SWZ(tile * 16 + n16, kgrp * 16));
            s8v a1l = *(const s8v*)(bufL + XS_SWZ(tile * 16 + n16, 64 + kgrp * 16));
            #pragma unroll
            for (int c4 = 0; c4 < 4; ++c4) {
                f4v acc = {0.f, 0.f, 0.f, 0.f};
                acc = __builtin_amdgcn_mfma_f32_16x16x32_bf16(a0h, woh[c4][0], acc, 0, 0, 0);
                acc = __builtin_amdgcn_mfma_f32_16x16x32_bf16(a1h, woh[c4][1], acc, 0, 0, 0);
                acc = __builtin_amdgcn_mfma_f32_16x16x32_bf16(a0l, woh[c4][0], acc, 0, 0, 0);
                acc = __builtin_amdgcn_mfma_f32_16x16x32_bf16(a1l, woh[c4][1], acc, 0, 0, 0);
                acc = __builtin_amdgcn_mfma_f32_16x16x32_bf16(a0h, wol[c4][0], acc, 0, 0, 0);
                acc = __builtin_amdgcn_mfma_f32_16x16x32_bf16(a1h, wol[c4][1], acc, 0, 0, 0);
                #pragma unroll
                for (int jj = 0; jj < 4; ++jj) {
                    int row = tile * 16 + kgrp * 4 + jj;
                    int s = s0 + row;
                    out[((size_t)s * R_LEN + r) * C_DIM + c4 * 16 + n16] = acc[jj] + boc[c4];
                }
            }
        }
    }
}

extern "C" void kernel_launch(void* const* d_in, const int* in_sizes, int n_in,
                              void* d_out, int out_size, void* d_ws, size_t ws_size,
                              hipStream_t stream) {
    const float* act = (const float*)d_in[0];
    // d_in[1] = msa_mask: unused by the math
    const float* lns = (const float*)d_in[2];
    const float* lnb = (const float*)d_in[3];
    const float* wq  = (const float*)d_in[4];
    const float* wk  = (const float*)d_in[5];
    const float* wv  = (const float*)d_in[6];
    const float* wg  = (const float*)d_in[7];
    const float* bg  = (const float*)d_in[8];
    const float* wo  = (const float*)d_in[9];
    const float* bo  = (const float*)d_in[10];
    float* out = (float*)d_out;

    float* o1g    = (float*)d_ws;                          // 98304 B
    float* qavg_g = (float*)((char*)d_ws + 98304);         // 98304 B
    u16*   kv_g   = (u16*)((char*)d_ws + 196608);          // 25165824 B

    hipMemsetAsync(qavg_g, 0, 98304, stream);
    hipLaunchKernelGGL(ka_lnkv, dim3(R_LEN, 16), dim3(256), 0, stream,
                       act, lns, lnb, wk, wv, kv_g, qavg_g);
    hipLaunchKernelGGL(kb_attn, dim3(R_LEN), dim3(256), 0, stream,
                       kv_g, qavg_g, wq, o1g);
    hipLaunchKernelGGL(kc_gateout, dim3(R_LEN, 16), dim3(256), 0, stream,
                       act, lns, lnb, wg, bg, wo, bo, o1g, out);
}